// Round 1
// baseline (3052.696 us; speedup 1.0000x reference)
//
#include <hip/hip_runtime.h>

#define N_NODES 200000
#define N_SUPER 20000
#define N_EDGES 640000
#define EMB 256

// ---------------------------------------------------------------------------
// Kernel 1: out = x  (x1 backing store; supernode rows patched by gemm_add)
// ---------------------------------------------------------------------------
__global__ __launch_bounds__(256) void copy_f4(const float4* __restrict__ s,
                                               float4* __restrict__ d, int n) {
    int i = blockIdx.x * 256 + threadIdx.x;
    if (i < n) d[i] = s[i];
}

// ---------------------------------------------------------------------------
// Tiled fp32 GEMM with fused scatter/bias epilogue.
//   out[row(m)][col0+c] += sum_k A[m][k] * W[col0+c][k] + bias[c] * coef(m)
//   row(m) = idx ? idx[m] : m       (idx rows are unique -> plain RMW ok)
//   coef(m) = deg ? deg[m] : 1.0f
// 64x64 tile, 256 threads, 4x4 register micro-tile, LDS-transposed operands
// so the inner loop is 2x ds_read_b128 + 16 v_fma_f32 per k.
// ---------------------------------------------------------------------------
__global__ __launch_bounds__(256) void gemm_add(
    const float* __restrict__ A, const float* __restrict__ W,
    const float* __restrict__ bias, const float* __restrict__ deg,
    const int* __restrict__ idx, float* __restrict__ out, int M) {
    // +4 pad keeps 16B alignment for float4 LDS reads and breaks bank strides
    __shared__ float At[64][68];
    __shared__ float Wt[64][68];
    const int row0 = blockIdx.x * 64;
    const int col0 = blockIdx.y * 64;
    const int tid = threadIdx.x;
    const int tr = tid >> 4, tc = tid & 15;
    float acc[4][4] = {};

    for (int k0 = 0; k0 < EMB; k0 += 64) {
        __syncthreads();
        // 64 rows x 16 float4 = 1024 slots for each tile; 4 slots/thread
        #pragma unroll
        for (int t = tid; t < 1024; t += 256) {
            int r = t >> 4, kq = t & 15;
            int m = row0 + r;
            float4 v = make_float4(0.f, 0.f, 0.f, 0.f);
            if (m < M) v = *(const float4*)(A + (size_t)m * EMB + k0 + kq * 4);
            At[kq * 4 + 0][r] = v.x; At[kq * 4 + 1][r] = v.y;
            At[kq * 4 + 2][r] = v.z; At[kq * 4 + 3][r] = v.w;
            float4 w = *(const float4*)(W + (size_t)(col0 + r) * EMB + k0 + kq * 4);
            Wt[kq * 4 + 0][r] = w.x; Wt[kq * 4 + 1][r] = w.y;
            Wt[kq * 4 + 2][r] = w.z; Wt[kq * 4 + 3][r] = w.w;
        }
        __syncthreads();
        #pragma unroll 8
        for (int k = 0; k < 64; ++k) {
            float4 a = *(const float4*)&At[k][tr * 4];
            float4 w = *(const float4*)&Wt[k][tc * 4];
            float av[4] = {a.x, a.y, a.z, a.w};
            float wv[4] = {w.x, w.y, w.z, w.w};
            #pragma unroll
            for (int i = 0; i < 4; ++i)
                #pragma unroll
                for (int j = 0; j < 4; ++j)
                    acc[i][j] += av[i] * wv[j];
        }
    }

    #pragma unroll
    for (int i = 0; i < 4; ++i) {
        int m = row0 + tr * 4 + i;
        if (m >= M) continue;
        int orow = idx ? idx[m] : m;
        float coef = deg ? deg[m] : 1.0f;
        float* op = out + (size_t)orow * EMB + col0 + tc * 4;
        #pragma unroll
        for (int j = 0; j < 4; ++j)
            op[j] += acc[i][j] + bias[col0 + tc * 4 + j] * coef;
    }
}

// ---------------------------------------------------------------------------
// Kernel: one wave per edge. Gather x1[src] (float4/lane, coalesced 1KB row),
// atomic-add into agg[dst]; lane 0 counts degree (as float for later use).
// Reads d_out (x1), writes only ws -> no read-after-partial-write hazard.
// ---------------------------------------------------------------------------
__global__ __launch_bounds__(256) void edge_agg(const int* __restrict__ ei,
                                                const float* __restrict__ x1,
                                                float* __restrict__ agg,
                                                float* __restrict__ deg) {
    int w = (blockIdx.x * 256 + threadIdx.x) >> 6;  // edge id
    int lane = threadIdx.x & 63;
    if (w >= N_EDGES) return;
    int d = ei[w];             // dst = row 0 of edge_index
    int s = ei[N_EDGES + w];   // src = row 1
    float4 v = *(const float4*)(x1 + (size_t)s * EMB + lane * 4);
    float* p = agg + (size_t)d * EMB + lane * 4;
    unsafeAtomicAdd(p + 0, v.x);
    unsafeAtomicAdd(p + 1, v.y);
    unsafeAtomicAdd(p + 2, v.z);
    unsafeAtomicAdd(p + 3, v.w);
    if (lane == 0) unsafeAtomicAdd(deg + d, 1.0f);
}

extern "C" void kernel_launch(void* const* d_in, const int* in_sizes, int n_in,
                              void* d_out, int out_size, void* d_ws, size_t ws_size,
                              hipStream_t stream) {
    const float* x    = (const float*)d_in[0];
    const float* snx  = (const float*)d_in[1];
    const int*   ei   = (const int*)d_in[2];    // [2, E] flat: row0=dst, row1=src
    const int*   sidx = (const int*)d_in[3];    // [S]
    const float* W1   = (const float*)d_in[5];
    const float* b1   = (const float*)d_in[6];
    const float* W2   = (const float*)d_in[7];
    const float* b2   = (const float*)d_in[8];
    float* out = (float*)d_out;

    float* agg = (float*)d_ws;                       // [N_NODES, EMB]
    float* deg = agg + (size_t)N_NODES * EMB;        // [N_NODES]

    // zero agg + deg
    hipMemsetAsync(d_ws, 0, ((size_t)N_NODES * EMB + N_NODES) * sizeof(float), stream);

    // out = x
    int n4 = N_NODES * EMB / 4;
    copy_f4<<<(n4 + 255) / 256, 256, 0, stream>>>((const float4*)x, (float4*)out, n4);

    // out[sidx] += snx @ W1^T + b1   (-> out now holds x1)
    dim3 g1((N_SUPER + 63) / 64, EMB / 64);
    gemm_add<<<g1, 256, 0, stream>>>(snx, W1, b1, nullptr, sidx, out, N_SUPER);

    // agg[dst] += x1[src]; deg[dst] += 1
    edge_agg<<<N_EDGES * 64 / 256, 256, 0, stream>>>(ei, out, agg, deg);

    // out += agg @ W2^T + deg * b2
    dim3 g2((N_NODES + 63) / 64, EMB / 64);
    gemm_add<<<g2, 256, 0, stream>>>(agg, W2, b2, deg, nullptr, out, N_NODES);
}

// Round 2
// 1038.760 us; speedup vs baseline: 2.9388x; 2.9388x over previous
//
#include <hip/hip_runtime.h>

#define N_NODES 200000
#define N_SUPER 20000
#define N_EDGES 640000
#define EMB 256

typedef unsigned short ushort_t;
typedef unsigned short ushort8 __attribute__((ext_vector_type(8)));

static __device__ __forceinline__ ushort_t f2bf(float f) {
    unsigned int b = __float_as_uint(f);
    unsigned int r = (b + 0x7FFFu + ((b >> 16) & 1u)) >> 16;  // RNE
    return (ushort_t)r;
}

// ---------------------------------------------------------------------------
// out = x
// ---------------------------------------------------------------------------
__global__ __launch_bounds__(256) void copy_f4(const float4* __restrict__ s,
                                               float4* __restrict__ d, int n) {
    int i = blockIdx.x * 256 + threadIdx.x;
    if (i < n) d[i] = s[i];
}

// ---------------------------------------------------------------------------
// CSR build: histogram -> scan (3 kernels) -> bucket fill
// ---------------------------------------------------------------------------
__global__ __launch_bounds__(256) void hist_dst(const int* __restrict__ ei,
                                                int* __restrict__ counts) {
    int e = blockIdx.x * 256 + threadIdx.x;
    if (e < N_EDGES) atomicAdd(&counts[ei[e]], 1);
}

__global__ __launch_bounds__(256) void block_sums(const int* __restrict__ counts,
                                                  int* __restrict__ partials, int N) {
    __shared__ int sh[256];
    int tid = threadIdx.x;
    int i = blockIdx.x * 256 + tid;
    sh[tid] = (i < N) ? counts[i] : 0;
    __syncthreads();
    for (int off = 128; off > 0; off >>= 1) {
        if (tid < off) sh[tid] += sh[tid + off];
        __syncthreads();
    }
    if (tid == 0) partials[blockIdx.x] = sh[0];
}

__global__ __launch_bounds__(256) void scan_partials(int* __restrict__ partials, int NB) {
    __shared__ int sh[256];
    int tid = threadIdx.x;
    int carry = 0;
    for (int c0 = 0; c0 < NB; c0 += 256) {
        int i = c0 + tid;
        int v = (i < NB) ? partials[i] : 0;
        sh[tid] = v;
        __syncthreads();
        for (int off = 1; off < 256; off <<= 1) {
            int t = (tid >= off) ? sh[tid - off] : 0;
            __syncthreads();
            sh[tid] += t;
            __syncthreads();
        }
        int incl = sh[tid];
        int total = sh[255];
        if (i < NB) partials[i] = carry + incl - v;  // exclusive
        carry += total;
        __syncthreads();
    }
}

__global__ __launch_bounds__(256) void scan_blocks(const int* __restrict__ counts,
                                                   const int* __restrict__ partials,
                                                   int* __restrict__ base, int N) {
    __shared__ int sh[256];
    int tid = threadIdx.x;
    int b = blockIdx.x;
    int i = b * 256 + tid;
    int c = (i < N) ? counts[i] : 0;
    sh[tid] = c;
    __syncthreads();
    for (int off = 1; off < 256; off <<= 1) {
        int t = (tid >= off) ? sh[tid - off] : 0;
        __syncthreads();
        sh[tid] += t;
        __syncthreads();
    }
    if (i < N) base[i] = partials[b] + sh[tid] - c;
    if (i == N - 1) base[N] = partials[b] + sh[tid];  // == N_EDGES
}

__global__ __launch_bounds__(256) void fill_bucket(const int* __restrict__ ei,
                                                   const int* __restrict__ base,
                                                   int* __restrict__ cursor,
                                                   int* __restrict__ bucket) {
    int e = blockIdx.x * 256 + threadIdx.x;
    if (e >= N_EDGES) return;
    int d = ei[e];             // dst = row 0
    int s = ei[N_EDGES + e];   // src = row 1
    int pos = atomicAdd(&cursor[d], 1);
    bucket[base[d] + pos] = s;
}

// ---------------------------------------------------------------------------
// Gather-sum: one wave per dst node, sum x1[src] rows, write agg row (bf16)
// exactly once. No fp32 atomics anywhere.
// ---------------------------------------------------------------------------
__global__ __launch_bounds__(256) void gather_sum(const int* __restrict__ bucket,
                                                  const int* __restrict__ base,
                                                  const float* __restrict__ x1,
                                                  ushort_t* __restrict__ agg) {
    int node = blockIdx.x * 4 + (threadIdx.x >> 6);
    int lane = threadIdx.x & 63;
    if (node >= N_NODES) return;
    int j0 = base[node], j1 = base[node + 1];
    float4 acc = make_float4(0.f, 0.f, 0.f, 0.f);
    for (int j = j0; j < j1; ++j) {
        int s = bucket[j];  // wave-uniform -> broadcast load
        float4 v = *(const float4*)(x1 + (size_t)s * EMB + lane * 4);
        acc.x += v.x; acc.y += v.y; acc.z += v.z; acc.w += v.w;
    }
    ushort4 p;
    p.x = f2bf(acc.x); p.y = f2bf(acc.y); p.z = f2bf(acc.z); p.w = f2bf(acc.w);
    *(ushort4*)(agg + (size_t)node * EMB + lane * 4) = p;
}

// ---------------------------------------------------------------------------
// Tiled fp32 GEMM with fused scatter/bias epilogue; A is fp32 or bf16.
//   out[row(m)][col0+c] += sum_k A[m][k]*W[col0+c][k] + bias[c]*coef(m)
//   row(m) = idx ? idx[m] : m ; coef(m) = deg ? (float)deg[m] : 1.0f
// ---------------------------------------------------------------------------
template <bool A_BF16>
__global__ __launch_bounds__(256) void gemm_add(
    const void* __restrict__ Ap, const float* __restrict__ W,
    const float* __restrict__ bias, const int* __restrict__ deg,
    const int* __restrict__ idx, float* __restrict__ out, int M) {
    __shared__ float At[64][68];
    __shared__ float Wt[64][68];
    const int row0 = blockIdx.x * 64;
    const int col0 = blockIdx.y * 64;
    const int tid = threadIdx.x;
    const int tr = tid >> 4, tc = tid & 15;
    float acc[4][4] = {};

    for (int k0 = 0; k0 < EMB; k0 += 64) {
        __syncthreads();
        if constexpr (A_BF16) {
            const ushort_t* A = (const ushort_t*)Ap;
            for (int t = tid; t < 512; t += 256) {   // 64 rows x 8 ushort8
                int r = t >> 3, kq = t & 7;
                int m = row0 + r;
                float vals[8] = {0, 0, 0, 0, 0, 0, 0, 0};
                if (m < M) {
                    ushort8 u = *(const ushort8*)(A + (size_t)m * EMB + k0 + kq * 8);
                    #pragma unroll
                    for (int j = 0; j < 8; ++j)
                        vals[j] = __uint_as_float((unsigned int)u[j] << 16);
                }
                #pragma unroll
                for (int j = 0; j < 8; ++j) At[kq * 8 + j][r] = vals[j];
            }
        } else {
            const float* A = (const float*)Ap;
            for (int t = tid; t < 1024; t += 256) {  // 64 rows x 16 float4
                int r = t >> 4, kq = t & 15;
                int m = row0 + r;
                float4 v = make_float4(0.f, 0.f, 0.f, 0.f);
                if (m < M) v = *(const float4*)(A + (size_t)m * EMB + k0 + kq * 4);
                At[kq * 4 + 0][r] = v.x; At[kq * 4 + 1][r] = v.y;
                At[kq * 4 + 2][r] = v.z; At[kq * 4 + 3][r] = v.w;
            }
        }
        for (int t = tid; t < 1024; t += 256) {      // W tile: 64 rows x 16 float4
            int r = t >> 4, kq = t & 15;
            float4 w = *(const float4*)(W + (size_t)(col0 + r) * EMB + k0 + kq * 4);
            Wt[kq * 4 + 0][r] = w.x; Wt[kq * 4 + 1][r] = w.y;
            Wt[kq * 4 + 2][r] = w.z; Wt[kq * 4 + 3][r] = w.w;
        }
        __syncthreads();
        #pragma unroll 8
        for (int k = 0; k < 64; ++k) {
            float4 a = *(const float4*)&At[k][tr * 4];
            float4 w = *(const float4*)&Wt[k][tc * 4];
            float av[4] = {a.x, a.y, a.z, a.w};
            float wv[4] = {w.x, w.y, w.z, w.w};
            #pragma unroll
            for (int i = 0; i < 4; ++i)
                #pragma unroll
                for (int j = 0; j < 4; ++j)
                    acc[i][j] += av[i] * wv[j];
        }
    }

    #pragma unroll
    for (int i = 0; i < 4; ++i) {
        int m = row0 + tr * 4 + i;
        if (m >= M) continue;
        int orow = idx ? idx[m] : m;
        float coef = deg ? (float)deg[m] : 1.0f;
        float* op = out + (size_t)orow * EMB + col0 + tc * 4;
        #pragma unroll
        for (int j = 0; j < 4; ++j)
            op[j] += acc[i][j] + bias[col0 + tc * 4 + j] * coef;
    }
}

extern "C" void kernel_launch(void* const* d_in, const int* in_sizes, int n_in,
                              void* d_out, int out_size, void* d_ws, size_t ws_size,
                              hipStream_t stream) {
    const float* x    = (const float*)d_in[0];
    const float* snx  = (const float*)d_in[1];
    const int*   ei   = (const int*)d_in[2];    // [2, E] flat: row0=dst, row1=src
    const int*   sidx = (const int*)d_in[3];    // [S]
    const float* W1   = (const float*)d_in[5];
    const float* b1   = (const float*)d_in[6];
    const float* W2   = (const float*)d_in[7];
    const float* b2   = (const float*)d_in[8];
    float* out = (float*)d_out;

    // ws layout (total ~107.4 MB):
    ushort_t* agg  = (ushort_t*)d_ws;                       // [N_NODES*EMB] bf16
    int* counts    = (int*)(agg + (size_t)N_NODES * EMB);   // [N_NODES] (= deg)
    int* cursor    = counts + N_NODES;                      // [N_NODES]
    int* base      = cursor + N_NODES;                      // [N_NODES+1]
    int* bucket    = base + (N_NODES + 1);                  // [N_EDGES]
    int* partials  = bucket + N_EDGES;                      // [1024]

    const int NB = (N_NODES + 255) / 256;  // 782

    // zero counts + cursor (adjacent, 1.6 MB)
    hipMemsetAsync(counts, 0, 2 * N_NODES * sizeof(int), stream);

    // out = x
    int n4 = N_NODES * EMB / 4;
    copy_f4<<<(n4 + 255) / 256, 256, 0, stream>>>((const float4*)x, (float4*)out, n4);

    // out[sidx] += snx @ W1^T + b1   (-> out now holds x1)
    dim3 g1((N_SUPER + 63) / 64, EMB / 64);
    gemm_add<false><<<g1, 256, 0, stream>>>(snx, W1, b1, nullptr, sidx, out, N_SUPER);

    // CSR build by dst
    hist_dst<<<(N_EDGES + 255) / 256, 256, 0, stream>>>(ei, counts);
    block_sums<<<NB, 256, 0, stream>>>(counts, partials, N_NODES);
    scan_partials<<<1, 256, 0, stream>>>(partials, NB);
    scan_blocks<<<NB, 256, 0, stream>>>(counts, partials, base, N_NODES);
    fill_bucket<<<(N_EDGES + 255) / 256, 256, 0, stream>>>(ei, base, cursor, bucket);

    // agg[n] = sum_{e: dst=n} x1[src_e]   (bf16 rows, written once)
    gather_sum<<<(N_NODES + 3) / 4, 256, 0, stream>>>(bucket, base, out, agg);

    // out += agg @ W2^T + deg * b2
    dim3 g2((N_NODES + 63) / 64, EMB / 64);
    gemm_add<true><<<g2, 256, 0, stream>>>(agg, W2, b2, counts, nullptr, out, N_NODES);
}